// Round 1
// baseline (639.774 us; speedup 1.0000x reference)
//
#include <hip/hip_runtime.h>

typedef unsigned int u32;
typedef unsigned long long u64;

#define N_IMG 32
#define NA 67200
#define KTOP 1024
#define IM_F 1280.0f

// Correctly-rounded f32 exp via double (matches any faithful reference exp
// at virtually every point).
__device__ __forceinline__ float cr_expf(float x) { return (float)exp((double)x); }

// ---------------- K1: softmax face score, exact f32 chain ----------------
__global__ void score_kernel(const float2* __restrict__ conf, float* __restrict__ scores) {
    int id = blockIdx.x * blockDim.x + threadIdx.x;
    if (id >= N_IMG * NA) return;
    float2 c = conf[id];
    float m  = fmaxf(c.x, c.y);
    float e0 = cr_expf(c.x - m);   // one of these is exp(0)=1 exactly
    float e1 = cr_expf(c.y - m);
    scores[id] = e1 / (e0 + e1);
}

// ---------------- K2: exact stable top-1024 per image ----------------
// Radix-select on uint bits (all scores >= 0 -> uint order == float order),
// then bitonic sort of keys (score_bits<<32)|~idx descending
// == score desc, index asc (jax.lax.top_k tie semantics).
__global__ __launch_bounds__(1024) void topk_kernel(const float* __restrict__ scores,
                                                    u32* __restrict__ top_idx,
                                                    float* __restrict__ top_score) {
    const int n   = blockIdx.x;
    const int tid = threadIdx.x;
    const float* s = scores + (size_t)n * NA;

    __shared__ u32 histA[2048];
    __shared__ u32 histB[2048];
    __shared__ u64 cand[KTOP];
    __shared__ u32 eq_idx[KTOP];
    __shared__ u32 sh_prefix;
    __shared__ int sh_R;
    __shared__ u32 sh_cntg, sh_cnte;

    if (tid == 0) { sh_prefix = 0; sh_R = KTOP; sh_cntg = 0; sh_cnte = 0; }
    __syncthreads();

    u32 prefmask = 0;
    #pragma unroll 1
    for (int r = 0; r < 3; ++r) {
        const int shift = (r == 0) ? 21 : (r == 1) ? 10 : 0;
        const int nb    = (r == 2) ? 1024 : 2048;

        for (int i = tid; i < nb; i += 1024) histA[i] = 0;
        __syncthreads();
        const u32 pref = sh_prefix;

        for (int a = tid; a < NA; a += 1024) {
            u32 u = __float_as_uint(s[a]);
            if ((u & prefmask) == pref)
                atomicAdd(&histA[(u >> shift) & (u32)(nb - 1)], 1u);
        }
        __syncthreads();

        // suffix sums: src[b] = count of field >= b (within prefix)
        u32 *src = histA, *dst = histB;
        for (int d = 1; d < nb; d <<= 1) {
            for (int i = tid; i < nb; i += 1024)
                dst[i] = src[i] + ((i + d < nb) ? src[i + d] : 0u);
            __syncthreads();
            u32* t = src; src = dst; dst = t;
        }

        const int R = sh_R;
        __syncthreads();
        for (int b = tid; b < nb; b += 1024) {
            int ge = (int)src[b];
            int gt = (b + 1 < nb) ? (int)src[b + 1] : 0;
            if (ge >= R && gt < R) {          // unique crossing
                sh_prefix = pref | ((u32)b << shift);
                sh_R = R - gt;
            }
        }
        __syncthreads();
        prefmask |= (u32)(nb - 1) << shift;
    }

    const u32 V  = sh_prefix;   // exact value at rank KTOP
    const int R3 = sh_R;        // rank within the ==V class
    (void)R3;

    // compaction: strictly-greater into cand, equals into eq list
    for (int a = tid; a < NA; a += 1024) {
        u32 u = __float_as_uint(s[a]);
        if (u > V) {
            u32 p = atomicAdd(&sh_cntg, 1u);
            cand[p] = ((u64)u << 32) | (u32)(~(u32)a);
        } else if (u == V) {
            u32 p = atomicAdd(&sh_cnte, 1u);
            if (p < KTOP) eq_idx[p] = a;
        }
    }
    __syncthreads();

    const int G    = (int)sh_cntg;            // == KTOP - R3
    const int ce   = min((int)sh_cnte, KTOP);
    const int need = KTOP - G;
    // pick the `need` smallest indices among equals via rank counting
    for (int t = tid; t < ce; t += 1024) {
        u32 my = eq_idx[t];
        int rank = 0;
        for (int j = 0; j < ce; ++j) rank += (eq_idx[j] < my);
        if (rank < need) cand[G + rank] = ((u64)V << 32) | (u32)(~my);
    }

    // bitonic sort descending, 1024 elements
    for (int k = 2; k <= KTOP; k <<= 1) {
        for (int j = k >> 1; j > 0; j >>= 1) {
            __syncthreads();
            int i = tid;
            int ixj = i ^ j;
            if (ixj > i) {
                u64 a_ = cand[i], b_ = cand[ixj];
                bool sw = ((i & k) == 0) ? (a_ < b_) : (a_ > b_);
                if (sw) { cand[i] = b_; cand[ixj] = a_; }
            }
        }
    }
    __syncthreads();

    u64 c = cand[tid];
    top_idx[n * KTOP + tid]   = ~(u32)(c & 0xFFFFFFFFull);
    top_score[n * KTOP + tid] = __uint_as_float((u32)(c >> 32));
}

// ---------------- K3: gather + decode boxes/landmarks ----------------
__global__ void decode_kernel(const float* __restrict__ loc, const float* __restrict__ landms,
                              const float* __restrict__ priors, const u32* __restrict__ top_idx,
                              const float* __restrict__ top_score, float* __restrict__ det) {
    int id = blockIdx.x * blockDim.x + threadIdx.x;
    if (id >= N_IMG * KTOP) return;
    int n = id >> 10;
    u32 a = top_idx[id];
    float4 p = *(const float4*)(priors + (size_t)a * 4);
    float4 l = *(const float4*)(loc + ((size_t)n * NA + a) * 4);

    float cx = p.x + l.x * 0.1f * p.z;
    float cy = p.y + l.y * 0.1f * p.w;
    float w  = p.z * cr_expf(l.z * 0.2f);
    float h  = p.w * cr_expf(l.w * 0.2f);

    float* o = det + (size_t)id * 15;
    o[0] = (cx - w * 0.5f) * IM_F;
    o[1] = (cy - h * 0.5f) * IM_F;
    o[2] = (cx + w * 0.5f) * IM_F;
    o[3] = (cy + h * 0.5f) * IM_F;
    o[4] = top_score[id];

    const float* mp = landms + ((size_t)n * NA + a) * 10;
    #pragma unroll
    for (int q = 0; q < 5; ++q) {
        o[5 + 2 * q]     = (p.x + mp[2 * q]     * 0.1f * p.z) * IM_F;
        o[5 + 2 * q + 1] = (p.y + mp[2 * q + 1] * 0.1f * p.w) * IM_F;
    }
}

// ---------------- K4: IoU suppression bitmask (j > i only) ----------------
__global__ __launch_bounds__(256) void mask_kernel(const float* __restrict__ det,
                                                   u64* __restrict__ mask) {
    const int bid = blockIdx.x;       // 32 images x 4 row-chunks
    const int n = bid >> 2;
    const int chunk = bid & 3;
    const int tid = threadIdx.x;
    __shared__ float bx1[KTOP], by1[KTOP], bx2[KTOP], by2[KTOP], ba[KTOP];

    for (int j = tid; j < KTOP; j += 256) {
        const float* dr = det + ((size_t)n * KTOP + j) * 15;
        float x1 = dr[0], y1 = dr[1], x2 = dr[2], y2 = dr[3];
        bx1[j] = x1; by1[j] = y1; bx2[j] = x2; by2[j] = y2;
        ba[j] = fmaxf(x2 - x1, 0.f) * fmaxf(y2 - y1, 0.f);
    }
    __syncthreads();

    for (int t = tid; t < 256 * 16; t += 256) {
        int il = t >> 4, w = t & 15;
        int i = chunk * 256 + il;
        u64 m = 0;
        if (w * 64 + 63 > i) {
            float x1i = bx1[i], y1i = by1[i], x2i = bx2[i], y2i = by2[i], ai = ba[i];
            for (int l = 0; l < 64; ++l) {
                int j = w * 64 + l;
                if (j > i) {
                    float xx1 = fmaxf(x1i, bx1[j]);
                    float yy1 = fmaxf(y1i, by1[j]);
                    float xx2 = fminf(x2i, bx2[j]);
                    float yy2 = fminf(y2i, by2[j]);
                    float inter = fmaxf(xx2 - xx1, 0.f) * fmaxf(yy2 - yy1, 0.f);
                    float iou = inter / (ai + ba[j] - inter + 1e-9f);   // ref formula order
                    if (iou > 0.4f) m |= (1ull << l);
                }
            }
        }
        mask[((size_t)n * KTOP + i) * 16 + w] = m;
    }
}

// ---------------- K5: sequential greedy reduction, one wave per image ----------------
__global__ __launch_bounds__(64) void nms_kernel(const float* __restrict__ top_score,
                                                 const u64* __restrict__ mask,
                                                 u64* __restrict__ keep) {
    const int n = blockIdx.x;
    const int lane = threadIdx.x;
    u64 myw = 0;
    for (int g = 0; g < 16; ++g) {
        u64 b = __ballot(top_score[n * KTOP + g * 64 + lane] > 0.5f);
        if (lane == g) myw = b;
    }
    const u64* mrow = mask + (size_t)n * KTOP * 16;
    for (int i = 0; i < KTOP; ++i) {
        u64 row = (lane < 16) ? mrow[(size_t)i * 16 + lane] : 0ull;  // unconditional stream, pipelines
        u64 w_i = __shfl(myw, i >> 6);
        if ((w_i >> (i & 63)) & 1ull) {
            if (lane < 16) myw &= ~row;
        }
    }
    if (lane < 16) keep[n * 16 + lane] = myw;
}

// ---------------- K6: masked output write ----------------
__global__ void out_kernel(const float* __restrict__ det, const u64* __restrict__ keep,
                           float* __restrict__ out) {
    int id = blockIdx.x * blockDim.x + threadIdx.x;
    if (id >= N_IMG * KTOP * 15) return;
    int row = id / 15;
    int n = row >> 10;
    int k = row & 1023;
    float kf = ((keep[n * 16 + (k >> 6)] >> (k & 63)) & 1ull) ? 1.0f : 0.0f;
    out[id] = det[id] * kf;
}

extern "C" void kernel_launch(void* const* d_in, const int* in_sizes, int n_in,
                              void* d_out, int out_size, void* d_ws, size_t ws_size,
                              hipStream_t stream) {
    const float* loc    = (const float*)d_in[0];
    const float* conf   = (const float*)d_in[1];
    const float* landms = (const float*)d_in[2];
    const float* priors = (const float*)d_in[3];

    char* ws = (char*)d_ws;
    size_t off = 0;
    auto carve = [&](size_t bytes) { void* p = ws + off; off = (off + bytes + 255) & ~255ull; return p; };
    float* scores    = (float*)carve(sizeof(float) * (size_t)N_IMG * NA);
    u32*   top_idx   = (u32*)  carve(sizeof(u32)   * N_IMG * KTOP);
    float* top_score = (float*)carve(sizeof(float) * N_IMG * KTOP);
    float* det       = (float*)carve(sizeof(float) * N_IMG * KTOP * 15);
    u64*   mask      = (u64*)  carve(sizeof(u64)   * (size_t)N_IMG * KTOP * 16);
    u64*   keep      = (u64*)  carve(sizeof(u64)   * N_IMG * 16);

    score_kernel<<<(N_IMG * NA + 255) / 256, 256, 0, stream>>>((const float2*)conf, scores);
    topk_kernel<<<N_IMG, 1024, 0, stream>>>(scores, top_idx, top_score);
    decode_kernel<<<(N_IMG * KTOP + 255) / 256, 256, 0, stream>>>(loc, landms, priors, top_idx, top_score, det);
    mask_kernel<<<N_IMG * 4, 256, 0, stream>>>(det, mask);
    nms_kernel<<<N_IMG, 64, 0, stream>>>(top_score, mask, keep);
    out_kernel<<<(N_IMG * KTOP * 15 + 255) / 256, 256, 0, stream>>>(det, keep, (float*)d_out);
}

// Round 2
// 296.614 us; speedup vs baseline: 2.1569x; 2.1569x over previous
//
#include <hip/hip_runtime.h>

typedef unsigned int u32;
typedef unsigned long long u64;

#define N_IMG 32
#define NA 67200
#define KTOP 1024
#define IM_F 1280.0f

// Correctly-rounded f32 exp via double (matches any faithful reference exp
// at virtually every point).
__device__ __forceinline__ float cr_expf(float x) { return (float)exp((double)x); }

__device__ __forceinline__ u64 readlane64(u64 v, int lane) {
    u32 lo = (u32)__builtin_amdgcn_readlane((int)(u32)v, lane);
    u32 hi = (u32)__builtin_amdgcn_readlane((int)(u32)(v >> 32), lane);
    return ((u64)hi << 32) | (u64)lo;
}

// ---------------- K1: softmax face score, exact f32 chain ----------------
__global__ void score_kernel(const float2* __restrict__ conf, float* __restrict__ scores) {
    int id = blockIdx.x * blockDim.x + threadIdx.x;
    if (id >= N_IMG * NA) return;
    float2 c = conf[id];
    float m  = fmaxf(c.x, c.y);
    float e0 = cr_expf(c.x - m);   // one of these is exp(0)=1 exactly
    float e1 = cr_expf(c.y - m);
    scores[id] = e1 / (e0 + e1);
}

// ---------------- K2: exact stable top-1024 per image ----------------
// Radix-select on uint bits (all scores >= 0 -> uint order == float order),
// then bitonic sort of keys (score_bits<<32)|~idx descending
// == score desc, index asc (jax.lax.top_k tie semantics).
// Histogram is privatized 4x to cut same-address LDS atomic serialization.
__global__ __launch_bounds__(1024) void topk_kernel(const float* __restrict__ scores,
                                                    u32* __restrict__ top_idx,
                                                    float* __restrict__ top_score) {
    const int n   = blockIdx.x;
    const int tid = threadIdx.x;
    const float* s = scores + (size_t)n * NA;

    __shared__ u32 histA[2048 * 4];   // 4 replicas, interleaved
    __shared__ u32 histR[2048];
    __shared__ u32 histB[2048];
    __shared__ u64 cand[KTOP];
    __shared__ u32 eq_idx[KTOP];
    __shared__ u32 sh_prefix;
    __shared__ int sh_R;
    __shared__ u32 sh_cntg, sh_cnte;

    if (tid == 0) { sh_prefix = 0; sh_R = KTOP; sh_cntg = 0; sh_cnte = 0; }
    __syncthreads();

    const int rep = tid & 3;
    u32 prefmask = 0;
    #pragma unroll 1
    for (int r = 0; r < 3; ++r) {
        const int shift = (r == 0) ? 21 : (r == 1) ? 10 : 0;
        const int nb    = (r == 2) ? 1024 : 2048;

        for (int i = tid; i < nb * 4; i += 1024) histA[i] = 0;
        __syncthreads();
        const u32 pref = sh_prefix;

        for (int a = tid; a < NA; a += 1024) {
            u32 u = __float_as_uint(s[a]);
            if ((u & prefmask) == pref)
                atomicAdd(&histA[((((u >> shift) & (u32)(nb - 1)) << 2) | rep)], 1u);
        }
        __syncthreads();

        for (int i = tid; i < nb; i += 1024)
            histR[i] = histA[4 * i] + histA[4 * i + 1] + histA[4 * i + 2] + histA[4 * i + 3];
        __syncthreads();

        // suffix sums: src[b] = count of field >= b (within prefix)
        u32 *src = histR, *dst = histB;
        for (int d = 1; d < nb; d <<= 1) {
            for (int i = tid; i < nb; i += 1024)
                dst[i] = src[i] + ((i + d < nb) ? src[i + d] : 0u);
            __syncthreads();
            u32* t = src; src = dst; dst = t;
        }

        const int R = sh_R;
        __syncthreads();
        for (int b = tid; b < nb; b += 1024) {
            int ge = (int)src[b];
            int gt = (b + 1 < nb) ? (int)src[b + 1] : 0;
            if (ge >= R && gt < R) {          // unique crossing
                sh_prefix = pref | ((u32)b << shift);
                sh_R = R - gt;
            }
        }
        __syncthreads();
        prefmask |= (u32)(nb - 1) << shift;
    }

    const u32 V = sh_prefix;   // exact value at rank KTOP

    // compaction: strictly-greater into cand, equals into eq list
    for (int a = tid; a < NA; a += 1024) {
        u32 u = __float_as_uint(s[a]);
        if (u > V) {
            u32 p = atomicAdd(&sh_cntg, 1u);
            cand[p] = ((u64)u << 32) | (u32)(~(u32)a);
        } else if (u == V) {
            u32 p = atomicAdd(&sh_cnte, 1u);
            if (p < KTOP) eq_idx[p] = a;
        }
    }
    __syncthreads();

    const int G    = (int)sh_cntg;
    const int ce   = min((int)sh_cnte, KTOP);
    const int need = KTOP - G;
    // pick the `need` smallest indices among equals via rank counting
    for (int t = tid; t < ce; t += 1024) {
        u32 my = eq_idx[t];
        int rank = 0;
        for (int j = 0; j < ce; ++j) rank += (eq_idx[j] < my);
        if (rank < need) cand[G + rank] = ((u64)V << 32) | (u32)(~my);
    }

    // bitonic sort descending, 1024 elements
    for (int k = 2; k <= KTOP; k <<= 1) {
        for (int j = k >> 1; j > 0; j >>= 1) {
            __syncthreads();
            int i = tid;
            int ixj = i ^ j;
            if (ixj > i) {
                u64 a_ = cand[i], b_ = cand[ixj];
                bool sw = ((i & k) == 0) ? (a_ < b_) : (a_ > b_);
                if (sw) { cand[i] = b_; cand[ixj] = a_; }
            }
        }
    }
    __syncthreads();

    u64 c = cand[tid];
    top_idx[n * KTOP + tid]   = ~(u32)(c & 0xFFFFFFFFull);
    top_score[n * KTOP + tid] = __uint_as_float((u32)(c >> 32));
}

// ---------------- K3: gather + decode boxes/landmarks ----------------
__global__ void decode_kernel(const float* __restrict__ loc, const float* __restrict__ landms,
                              const float* __restrict__ priors, const u32* __restrict__ top_idx,
                              const float* __restrict__ top_score, float* __restrict__ det) {
    int id = blockIdx.x * blockDim.x + threadIdx.x;
    if (id >= N_IMG * KTOP) return;
    int n = id >> 10;
    u32 a = top_idx[id];
    float4 p = *(const float4*)(priors + (size_t)a * 4);
    float4 l = *(const float4*)(loc + ((size_t)n * NA + a) * 4);

    float cx = p.x + l.x * 0.1f * p.z;
    float cy = p.y + l.y * 0.1f * p.w;
    float w  = p.z * cr_expf(l.z * 0.2f);
    float h  = p.w * cr_expf(l.w * 0.2f);

    float* o = det + (size_t)id * 15;
    o[0] = (cx - w * 0.5f) * IM_F;
    o[1] = (cy - h * 0.5f) * IM_F;
    o[2] = (cx + w * 0.5f) * IM_F;
    o[3] = (cy + h * 0.5f) * IM_F;
    o[4] = top_score[id];

    const float* mp = landms + ((size_t)n * NA + a) * 10;
    #pragma unroll
    for (int q = 0; q < 5; ++q) {
        o[5 + 2 * q]     = (p.x + mp[2 * q]     * 0.1f * p.z) * IM_F;
        o[5 + 2 * q + 1] = (p.y + mp[2 * q + 1] * 0.1f * p.w) * IM_F;
    }
}

// ---------------- K4: IoU suppression bitmask (j > i only) ----------------
__global__ __launch_bounds__(256) void mask_kernel(const float* __restrict__ det,
                                                   u64* __restrict__ mask) {
    const int bid = blockIdx.x;       // 32 images x 8 row-chunks
    const int n = bid >> 3;
    const int chunk = bid & 7;
    const int tid = threadIdx.x;
    __shared__ float bx1[KTOP], by1[KTOP], bx2[KTOP], by2[KTOP], ba[KTOP];

    for (int j = tid; j < KTOP; j += 256) {
        const float* dr = det + ((size_t)n * KTOP + j) * 15;
        float x1 = dr[0], y1 = dr[1], x2 = dr[2], y2 = dr[3];
        bx1[j] = x1; by1[j] = y1; bx2[j] = x2; by2[j] = y2;
        ba[j] = fmaxf(x2 - x1, 0.f) * fmaxf(y2 - y1, 0.f);
    }
    __syncthreads();

    for (int t = tid; t < 128 * 16; t += 256) {
        int il = t >> 4, w = t & 15;
        int i = chunk * 128 + il;
        u64 m = 0;
        if (w * 64 + 63 > i) {
            float x1i = bx1[i], y1i = by1[i], x2i = bx2[i], y2i = by2[i], ai = ba[i];
            for (int l = 0; l < 64; ++l) {
                int j = w * 64 + l;
                if (j > i) {
                    float xx1 = fmaxf(x1i, bx1[j]);
                    float yy1 = fmaxf(y1i, by1[j]);
                    float xx2 = fminf(x2i, bx2[j]);
                    float yy2 = fminf(y2i, by2[j]);
                    float inter = fmaxf(xx2 - xx1, 0.f) * fmaxf(yy2 - yy1, 0.f);
                    float iou = inter / (ai + ba[j] - inter + 1e-9f);   // ref formula order
                    if (iou > 0.4f) m |= (1ull << l);
                }
            }
        }
        mask[((size_t)n * KTOP + i) * 16 + w] = m;
    }
}

// ---------------- K5: LDS-staged sequential greedy NMS + fused masked output ----
// Mask staged in two 64KB halves. Serial chain is scalar: per 64-row group the
// keep-word lives in an SGPR (readlane); kept rows update it via readlane +
// s_andn2; skipped rows cost one s_bittest. LDS row reads are unconditional ->
// prefetchable under unroll.
__global__ __launch_bounds__(1024) void nms_out_kernel(const float* __restrict__ top_score,
                                                       const u64* __restrict__ mask,
                                                       const float* __restrict__ det,
                                                       float* __restrict__ out) {
    const int n = blockIdx.x;
    const int tid = threadIdx.x;
    __shared__ u64 lmask[512 * 16];   // 64 KB: one half of the 1024x1024-bit mask

    const u64* mbase = mask + (size_t)n * KTOP * 16;
    u64 myw = 0;
    if (tid < 64) {
        const int lane = tid;
        for (int g = 0; g < 16; ++g) {
            u64 b = __ballot(top_score[n * KTOP + g * 64 + lane] > 0.5f);
            if (lane == g) myw = b;
        }
    }

    #pragma unroll 1
    for (int half = 0; half < 2; ++half) {
        __syncthreads();   // protect lmask from previous half's readers
        #pragma unroll
        for (int k = 0; k < 8; ++k) {
            int idx = tid + k * 1024;
            lmask[idx] = mbase[(size_t)half * 8192 + idx];
        }
        __syncthreads();
        if (tid < 64) {
            const int lane = tid;
            for (int g = half * 8; g < half * 8 + 8; ++g) {
                u64 kw = readlane64(myw, g);   // group's current keep bits -> SGPR
                const int rbase = (g * 64 - half * 512) * 16;
                #pragma unroll 8
                for (int l = 0; l < 64; ++l) {
                    u64 row = lmask[rbase + l * 16 + (lane & 15)];
                    if ((kw >> l) & 1ull) {
                        kw &= ~readlane64(row, g);       // in-group forward suppress
                        if (lane < 16) myw &= ~row;      // global forward suppress
                    }
                }
            }
        }
    }
    __syncthreads();
    if (tid < 16) lmask[tid] = myw;   // publish keep bits (mask rows no longer needed)
    __syncthreads();

    // masked output write: 15360 floats per image, element-parallel (coalesced)
    const float* drow = det + (size_t)n * KTOP * 15;
    float* orow = out + (size_t)n * KTOP * 15;
    for (int e = tid; e < KTOP * 15; e += 1024) {
        int k = e / 15;
        float f = ((lmask[k >> 6] >> (k & 63)) & 1ull) ? 1.0f : 0.0f;
        orow[e] = drow[e] * f;
    }
}

extern "C" void kernel_launch(void* const* d_in, const int* in_sizes, int n_in,
                              void* d_out, int out_size, void* d_ws, size_t ws_size,
                              hipStream_t stream) {
    const float* loc    = (const float*)d_in[0];
    const float* conf   = (const float*)d_in[1];
    const float* landms = (const float*)d_in[2];
    const float* priors = (const float*)d_in[3];

    char* ws = (char*)d_ws;
    size_t off = 0;
    auto carve = [&](size_t bytes) { void* p = ws + off; off = (off + bytes + 255) & ~255ull; return p; };
    float* scores    = (float*)carve(sizeof(float) * (size_t)N_IMG * NA);
    u32*   top_idx   = (u32*)  carve(sizeof(u32)   * N_IMG * KTOP);
    float* top_score = (float*)carve(sizeof(float) * N_IMG * KTOP);
    float* det       = (float*)carve(sizeof(float) * N_IMG * KTOP * 15);
    u64*   mask      = (u64*)  carve(sizeof(u64)   * (size_t)N_IMG * KTOP * 16);

    score_kernel<<<(N_IMG * NA + 255) / 256, 256, 0, stream>>>((const float2*)conf, scores);
    topk_kernel<<<N_IMG, 1024, 0, stream>>>(scores, top_idx, top_score);
    decode_kernel<<<(N_IMG * KTOP + 255) / 256, 256, 0, stream>>>(loc, landms, priors, top_idx, top_score, det);
    mask_kernel<<<N_IMG * 8, 256, 0, stream>>>(det, mask);
    nms_out_kernel<<<N_IMG, 1024, 0, stream>>>(top_score, mask, det, (float*)d_out);
}

// Round 3
// 192.922 us; speedup vs baseline: 3.3162x; 1.5375x over previous
//
#include <hip/hip_runtime.h>

typedef unsigned int u32;
typedef unsigned long long u64;

#define N_IMG 32
#define NA 67200
#define KTOP 1024
#define IM_F 1280.0f

// Correctly-rounded f32 exp via double (matches any faithful reference exp
// at virtually every point).
__device__ __forceinline__ float cr_expf(float x) { return (float)exp((double)x); }

__device__ __forceinline__ u64 readlane64(u64 v, int lane) {
    u32 lo = (u32)__builtin_amdgcn_readlane((int)(u32)v, lane);
    u32 hi = (u32)__builtin_amdgcn_readlane((int)(u32)(v >> 32), lane);
    return ((u64)hi << 32) | (u64)lo;
}

// ---------------- K1: softmax face score, exact f32 chain ----------------
__global__ void score_kernel(const float2* __restrict__ conf, float* __restrict__ scores) {
    int id = blockIdx.x * blockDim.x + threadIdx.x;
    if (id >= N_IMG * NA) return;
    float2 c = conf[id];
    float m  = fmaxf(c.x, c.y);
    float e0 = cr_expf(c.x - m);   // one of these is exp(0)=1 exactly
    float e1 = cr_expf(c.y - m);
    scores[id] = e1 / (e0 + e1);
}

// ---------------- K2: exact stable top-1024 per image ----------------
// Radix-select on uint bits (all scores >= 0 -> uint order == float order),
// then bitonic sort of keys (score_bits<<32)|~idx descending
// == score desc, index asc (jax.lax.top_k tie semantics).
// Histogram is privatized 4x to cut same-address LDS atomic serialization.
__global__ __launch_bounds__(1024) void topk_kernel(const float* __restrict__ scores,
                                                    u32* __restrict__ top_idx,
                                                    float* __restrict__ top_score) {
    const int n   = blockIdx.x;
    const int tid = threadIdx.x;
    const float* s = scores + (size_t)n * NA;

    __shared__ u32 histA[2048 * 4];   // 4 replicas, interleaved
    __shared__ u32 histR[2048];
    __shared__ u32 histB[2048];
    __shared__ u64 cand[KTOP];
    __shared__ u32 eq_idx[KTOP];
    __shared__ u32 sh_prefix;
    __shared__ int sh_R;
    __shared__ u32 sh_cntg, sh_cnte;

    if (tid == 0) { sh_prefix = 0; sh_R = KTOP; sh_cntg = 0; sh_cnte = 0; }
    __syncthreads();

    const int rep = tid & 3;
    u32 prefmask = 0;
    #pragma unroll 1
    for (int r = 0; r < 3; ++r) {
        const int shift = (r == 0) ? 21 : (r == 1) ? 10 : 0;
        const int nb    = (r == 2) ? 1024 : 2048;

        for (int i = tid; i < nb * 4; i += 1024) histA[i] = 0;
        __syncthreads();
        const u32 pref = sh_prefix;

        for (int a = tid; a < NA; a += 1024) {
            u32 u = __float_as_uint(s[a]);
            if ((u & prefmask) == pref)
                atomicAdd(&histA[((((u >> shift) & (u32)(nb - 1)) << 2) | rep)], 1u);
        }
        __syncthreads();

        for (int i = tid; i < nb; i += 1024)
            histR[i] = histA[4 * i] + histA[4 * i + 1] + histA[4 * i + 2] + histA[4 * i + 3];
        __syncthreads();

        // suffix sums: src[b] = count of field >= b (within prefix)
        u32 *src = histR, *dst = histB;
        for (int d = 1; d < nb; d <<= 1) {
            for (int i = tid; i < nb; i += 1024)
                dst[i] = src[i] + ((i + d < nb) ? src[i + d] : 0u);
            __syncthreads();
            u32* t = src; src = dst; dst = t;
        }

        const int R = sh_R;
        __syncthreads();
        for (int b = tid; b < nb; b += 1024) {
            int ge = (int)src[b];
            int gt = (b + 1 < nb) ? (int)src[b + 1] : 0;
            if (ge >= R && gt < R) {          // unique crossing
                sh_prefix = pref | ((u32)b << shift);
                sh_R = R - gt;
            }
        }
        __syncthreads();
        prefmask |= (u32)(nb - 1) << shift;
    }

    const u32 V = sh_prefix;   // exact value at rank KTOP

    // compaction: strictly-greater into cand, equals into eq list
    for (int a = tid; a < NA; a += 1024) {
        u32 u = __float_as_uint(s[a]);
        if (u > V) {
            u32 p = atomicAdd(&sh_cntg, 1u);
            cand[p] = ((u64)u << 32) | (u32)(~(u32)a);
        } else if (u == V) {
            u32 p = atomicAdd(&sh_cnte, 1u);
            if (p < KTOP) eq_idx[p] = a;
        }
    }
    __syncthreads();

    const int G    = (int)sh_cntg;
    const int ce   = min((int)sh_cnte, KTOP);
    const int need = KTOP - G;
    // pick the `need` smallest indices among equals via rank counting
    for (int t = tid; t < ce; t += 1024) {
        u32 my = eq_idx[t];
        int rank = 0;
        for (int j = 0; j < ce; ++j) rank += (eq_idx[j] < my);
        if (rank < need) cand[G + rank] = ((u64)V << 32) | (u32)(~my);
    }

    // bitonic sort descending, 1024 elements
    for (int k = 2; k <= KTOP; k <<= 1) {
        for (int j = k >> 1; j > 0; j >>= 1) {
            __syncthreads();
            int i = tid;
            int ixj = i ^ j;
            if (ixj > i) {
                u64 a_ = cand[i], b_ = cand[ixj];
                bool sw = ((i & k) == 0) ? (a_ < b_) : (a_ > b_);
                if (sw) { cand[i] = b_; cand[ixj] = a_; }
            }
        }
    }
    __syncthreads();

    u64 c = cand[tid];
    top_idx[n * KTOP + tid]   = ~(u32)(c & 0xFFFFFFFFull);
    top_score[n * KTOP + tid] = __uint_as_float((u32)(c >> 32));
}

// ---------------- K3: gather + decode boxes/landmarks ----------------
__global__ void decode_kernel(const float* __restrict__ loc, const float* __restrict__ landms,
                              const float* __restrict__ priors, const u32* __restrict__ top_idx,
                              const float* __restrict__ top_score, float* __restrict__ det) {
    int id = blockIdx.x * blockDim.x + threadIdx.x;
    if (id >= N_IMG * KTOP) return;
    int n = id >> 10;
    u32 a = top_idx[id];
    float4 p = *(const float4*)(priors + (size_t)a * 4);
    float4 l = *(const float4*)(loc + ((size_t)n * NA + a) * 4);

    float cx = p.x + l.x * 0.1f * p.z;
    float cy = p.y + l.y * 0.1f * p.w;
    float w  = p.z * cr_expf(l.z * 0.2f);
    float h  = p.w * cr_expf(l.w * 0.2f);

    float* o = det + (size_t)id * 15;
    o[0] = (cx - w * 0.5f) * IM_F;
    o[1] = (cy - h * 0.5f) * IM_F;
    o[2] = (cx + w * 0.5f) * IM_F;
    o[3] = (cy + h * 0.5f) * IM_F;
    o[4] = top_score[id];

    const float* mp = landms + ((size_t)n * NA + a) * 10;
    #pragma unroll
    for (int q = 0; q < 5; ++q) {
        o[5 + 2 * q]     = (p.x + mp[2 * q]     * 0.1f * p.z) * IM_F;
        o[5 + 2 * q + 1] = (p.y + mp[2 * q + 1] * 0.1f * p.w) * IM_F;
    }
}

// ---------------- K4: IoU suppression bitmask, wave-per-row + ballot ----------
// Lane l computes IoU(i, j=w*64+l); __ballot assembles the u64 word directly.
// LDS reads are stride-1 across lanes (conflict-free, 2 lanes/bank) and the
// row-i box is a same-address broadcast. Wave q handles rows i === q (mod 64):
// row i=64k+q needs words k..15, so every wave does exactly sum(16-k)=136
// ballot-words -> perfect balance. Low words (w < i>>6) are zeroed explicitly
// (nms reads all 16 words; ws is poisoned, not zeroed).
__global__ __launch_bounds__(256) void mask_kernel(const float* __restrict__ det,
                                                   u64* __restrict__ mask) {
    const int n    = blockIdx.x >> 4;        // image
    const int sub  = blockIdx.x & 15;        // block within image
    const int wid  = threadIdx.x >> 6;       // wave in block
    const int lane = threadIdx.x & 63;
    const int q    = sub * 4 + wid;          // wave id within image, 0..63
    const int tid  = threadIdx.x;

    __shared__ float bx1[KTOP], by1[KTOP], bx2[KTOP], by2[KTOP], ba[KTOP];
    for (int j = tid; j < KTOP; j += 256) {
        const float* dr = det + ((size_t)n * KTOP + j) * 15;
        float x1 = dr[0], y1 = dr[1], x2 = dr[2], y2 = dr[3];
        bx1[j] = x1; by1[j] = y1; bx2[j] = x2; by2[j] = y2;
        ba[j] = fmaxf(x2 - x1, 0.f) * fmaxf(y2 - y1, 0.f);
    }
    __syncthreads();

    u64* mbase = mask + (size_t)n * KTOP * 16;
    #pragma unroll 1
    for (int k = 0; k < 16; ++k) {
        const int i = k * 64 + q;
        const float x1i = bx1[i], y1i = by1[i], x2i = bx2[i], y2i = by2[i], ai = ba[i];
        u64* orow = mbase + (size_t)i * 16;
        if (lane < k) orow[lane] = 0ull;               // zero low words
        #pragma unroll 1
        for (int w = k; w < 16; ++w) {
            const int j = w * 64 + lane;
            bool bit = false;
            if (j > i) {
                float xx1 = fmaxf(x1i, bx1[j]);
                float yy1 = fmaxf(y1i, by1[j]);
                float xx2 = fminf(x2i, bx2[j]);
                float yy2 = fminf(y2i, by2[j]);
                float inter = fmaxf(xx2 - xx1, 0.f) * fmaxf(yy2 - yy1, 0.f);
                float iou = inter / (ai + ba[j] - inter + 1e-9f);   // ref formula order
                bit = iou > 0.4f;
            }
            u64 m = __ballot(bit);
            if (lane == 0) orow[w] = m;
        }
    }
}

// ---------------- K5: LDS-staged sequential greedy NMS + fused masked output ----
// Mask staged in two 64KB halves. Serial chain is scalar: per 64-row group the
// keep-word lives in an SGPR (readlane); kept rows update it via readlane +
// s_andn2; skipped rows cost one s_bittest. LDS row reads are unconditional ->
// prefetchable under unroll.
__global__ __launch_bounds__(1024) void nms_out_kernel(const float* __restrict__ top_score,
                                                       const u64* __restrict__ mask,
                                                       const float* __restrict__ det,
                                                       float* __restrict__ out) {
    const int n = blockIdx.x;
    const int tid = threadIdx.x;
    __shared__ u64 lmask[512 * 16];   // 64 KB: one half of the 1024x1024-bit mask

    const u64* mbase = mask + (size_t)n * KTOP * 16;
    u64 myw = 0;
    if (tid < 64) {
        const int lane = tid;
        for (int g = 0; g < 16; ++g) {
            u64 b = __ballot(top_score[n * KTOP + g * 64 + lane] > 0.5f);
            if (lane == g) myw = b;
        }
    }

    #pragma unroll 1
    for (int half = 0; half < 2; ++half) {
        __syncthreads();   // protect lmask from previous half's readers
        #pragma unroll
        for (int k = 0; k < 8; ++k) {
            int idx = tid + k * 1024;
            lmask[idx] = mbase[(size_t)half * 8192 + idx];
        }
        __syncthreads();
        if (tid < 64) {
            const int lane = tid;
            for (int g = half * 8; g < half * 8 + 8; ++g) {
                u64 kw = readlane64(myw, g);   // group's current keep bits -> SGPR
                const int rbase = (g * 64 - half * 512) * 16;
                #pragma unroll 8
                for (int l = 0; l < 64; ++l) {
                    u64 row = lmask[rbase + l * 16 + (lane & 15)];
                    if ((kw >> l) & 1ull) {
                        kw &= ~readlane64(row, g);       // in-group forward suppress
                        if (lane < 16) myw &= ~row;      // global forward suppress
                    }
                }
            }
        }
    }
    __syncthreads();
    if (tid < 16) lmask[tid] = myw;   // publish keep bits (mask rows no longer needed)
    __syncthreads();

    // masked output write: 15360 floats per image, element-parallel (coalesced)
    const float* drow = det + (size_t)n * KTOP * 15;
    float* orow = out + (size_t)n * KTOP * 15;
    for (int e = tid; e < KTOP * 15; e += 1024) {
        int k = e / 15;
        float f = ((lmask[k >> 6] >> (k & 63)) & 1ull) ? 1.0f : 0.0f;
        orow[e] = drow[e] * f;
    }
}

extern "C" void kernel_launch(void* const* d_in, const int* in_sizes, int n_in,
                              void* d_out, int out_size, void* d_ws, size_t ws_size,
                              hipStream_t stream) {
    const float* loc    = (const float*)d_in[0];
    const float* conf   = (const float*)d_in[1];
    const float* landms = (const float*)d_in[2];
    const float* priors = (const float*)d_in[3];

    char* ws = (char*)d_ws;
    size_t off = 0;
    auto carve = [&](size_t bytes) { void* p = ws + off; off = (off + bytes + 255) & ~255ull; return p; };
    float* scores    = (float*)carve(sizeof(float) * (size_t)N_IMG * NA);
    u32*   top_idx   = (u32*)  carve(sizeof(u32)   * N_IMG * KTOP);
    float* top_score = (float*)carve(sizeof(float) * N_IMG * KTOP);
    float* det       = (float*)carve(sizeof(float) * N_IMG * KTOP * 15);
    u64*   mask      = (u64*)  carve(sizeof(u64)   * (size_t)N_IMG * KTOP * 16);

    score_kernel<<<(N_IMG * NA + 255) / 256, 256, 0, stream>>>((const float2*)conf, scores);
    topk_kernel<<<N_IMG, 1024, 0, stream>>>(scores, top_idx, top_score);
    decode_kernel<<<(N_IMG * KTOP + 255) / 256, 256, 0, stream>>>(loc, landms, priors, top_idx, top_score, det);
    mask_kernel<<<N_IMG * 16, 256, 0, stream>>>(det, mask);
    nms_out_kernel<<<N_IMG, 1024, 0, stream>>>(top_score, mask, det, (float*)d_out);
}